// Round 8
// baseline (264.691 us; speedup 1.0000x reference)
//
#include <hip/hip_runtime.h>

#define N_NODES   100000
#define N_EDGES   1600000
#define N_GRAPHS  128
#define HIDDEN    128
#define N_CLASSES 10

#define BSH   7                   // bucket = 128 nodes
#define BSZ   128
#define NBF   782                 // ceil(100000/128)
#define NBFP  1024                // padded (4 buckets per thread in scan)
#define CAP   2560                // mean fill 2048, sigma 45 -> +11 sigma
#define PCH   4096                // edges per partition block

typedef unsigned int   uint;
typedef unsigned short ushort;
typedef unsigned char  uchar;

// ---------------- partition edges by dst>>7; payload = (dst&127)<<17 | src
__global__ __launch_bounds__(256)
void k_part_dst(const int* __restrict__ src, const int* __restrict__ dst,
                unsigned* __restrict__ bcur, unsigned* __restrict__ tmp, int nE) {
    __shared__ unsigned hist[NBFP];     // histogram, then reused as bucket base
    __shared__ unsigned lcur[NBFP];
    __shared__ unsigned tsum[256];
    __shared__ unsigned stag[PCH];
    __shared__ ushort   stagB[PCH];
    int t = threadIdx.x;
    int e0 = blockIdx.x * PCH;
    int e1 = min(e0 + PCH, nE);
    for (int i = t; i < NBFP; i += 256) hist[i] = 0;
    __syncthreads();
    for (int e = e0 + t; e < e1; e += 256)
        atomicAdd(&hist[dst[e] >> BSH], 1u);
    __syncthreads();
    unsigned h0 = hist[4 * t], h1 = hist[4 * t + 1], h2 = hist[4 * t + 2], h3 = hist[4 * t + 3];
    unsigned mysum = h0 + h1 + h2 + h3;
    tsum[t] = mysum; __syncthreads();
    for (int off = 1; off < 256; off <<= 1) {
        unsigned add = (t >= off) ? tsum[t - off] : 0u;
        __syncthreads();
        tsum[t] += add;
        __syncthreads();
    }
    unsigned run = tsum[t] - mysum;
    unsigned hh[4] = {h0, h1, h2, h3};
    #pragma unroll
    for (int k = 0; k < 4; ++k) {
        unsigned b = 4 * t + k;
        lcur[b] = run;
        if (hh[k] > 0) {
            unsigned g = atomicAdd(&bcur[b], hh[k]);
            hist[b] = b * CAP + g - run;      // base (modular wrap cancels on +i)
        }
        run += hh[k];
    }
    __syncthreads();
    for (int e = e0 + t; e < e1; e += 256) {
        int d = dst[e], b = d >> BSH;
        unsigned p = atomicAdd(&lcur[b], 1u);
        stag[p]  = ((unsigned)(d & (BSZ - 1)) << 17) | (unsigned)src[e];
        stagB[p] = (ushort)b;
    }
    __syncthreads();
    int cnt = e1 - e0;
    for (int i = t; i < cnt; i += 256) {
        unsigned b = stagB[i];
        unsigned a = hist[b] + (unsigned)i;
        if (a < (b + 1u) * CAP) tmp[a] = stag[i];
    }
}

// ---------------- partition by src>>7; payload = src&127 (uchar, for outdeg)
__global__ __launch_bounds__(256)
void k_part_src(const int* __restrict__ src,
                unsigned* __restrict__ bcur, uchar* __restrict__ tmp, int nE) {
    __shared__ unsigned hist[NBFP];
    __shared__ unsigned lcur[NBFP];
    __shared__ unsigned tsum[256];
    __shared__ uchar    stag[PCH];
    __shared__ ushort   stagB[PCH];
    int t = threadIdx.x;
    int e0 = blockIdx.x * PCH;
    int e1 = min(e0 + PCH, nE);
    for (int i = t; i < NBFP; i += 256) hist[i] = 0;
    __syncthreads();
    for (int e = e0 + t; e < e1; e += 256)
        atomicAdd(&hist[src[e] >> BSH], 1u);
    __syncthreads();
    unsigned h0 = hist[4 * t], h1 = hist[4 * t + 1], h2 = hist[4 * t + 2], h3 = hist[4 * t + 3];
    unsigned mysum = h0 + h1 + h2 + h3;
    tsum[t] = mysum; __syncthreads();
    for (int off = 1; off < 256; off <<= 1) {
        unsigned add = (t >= off) ? tsum[t - off] : 0u;
        __syncthreads();
        tsum[t] += add;
        __syncthreads();
    }
    unsigned run = tsum[t] - mysum;
    unsigned hh[4] = {h0, h1, h2, h3};
    #pragma unroll
    for (int k = 0; k < 4; ++k) {
        unsigned b = 4 * t + k;
        lcur[b] = run;
        if (hh[k] > 0) {
            unsigned g = atomicAdd(&bcur[b], hh[k]);
            hist[b] = b * CAP + g - run;
        }
        run += hh[k];
    }
    __syncthreads();
    for (int e = e0 + t; e < e1; e += 256) {
        int s = src[e], b = s >> BSH;
        unsigned p = atomicAdd(&lcur[b], 1u);
        stag[p]  = (uchar)(s & (BSZ - 1));
        stagB[p] = (ushort)b;
    }
    __syncthreads();
    int cnt = e1 - e0;
    for (int i = t; i < cnt; i += 256) {
        unsigned b = stagB[i];
        unsigned a = hist[b] + (unsigned)i;
        if (a < (b + 1u) * CAP) tmp[a] = stag[i];
    }
}

// ------- per bucket: indeg (from tmp1) + outdeg (from tmp2) + ns + hs0
__global__ __launch_bounds__(256)
void k_ind_odeg(const unsigned* __restrict__ bcur1, const unsigned* __restrict__ tmp1,
                const unsigned* __restrict__ bcur2, const uchar* __restrict__ tmp2,
                unsigned* __restrict__ indeg, float* __restrict__ ns,
                float* __restrict__ hs0) {
    __shared__ unsigned cin[BSZ], cout[BSZ];
    int b = blockIdx.x, t = threadIdx.x;
    if (t < BSZ) { cin[t] = 0; cout[t] = 0; }
    __syncthreads();
    unsigned f1 = min(bcur1[b], (unsigned)CAP);
    const unsigned* tp1 = tmp1 + (size_t)b * CAP;
    for (unsigned i = t; i < f1; i += 256) atomicAdd(&cin[tp1[i] >> 17], 1u);
    unsigned f2 = min(bcur2[b], (unsigned)CAP);
    const uchar* tp2 = tmp2 + (size_t)b * CAP;
    for (unsigned i = t; i < f2; i += 256) atomicAdd(&cout[tp2[i]], 1u);
    __syncthreads();
    if (t < BSZ) {
        int n = b * BSZ + t;
        if (n < N_NODES) {
            unsigned ci = cin[t], co = cout[t];
            float nsv = rsqrtf(fmaxf((float)co, 1.0f));
            indeg[n] = ci;
            ns[n]    = nsv;
            hs0[n]   = (float)ci * nsv;
        }
    }
}

// ---- segment table: each block self-sorts breakpoints, then computes its row
//      U_s = (W1.m_s)@W2, V_s = (b1.m_s)@W2
__global__ void k_segtable(const float* __restrict__ W1, const float* __restrict__ b1,
                           const float* __restrict__ W2,
                           float* __restrict__ U, float* __restrict__ V) {
    __shared__ float s[128];
    int t = threadIdx.x;           // 128 threads
    {
        float w = W1[t], bb = b1[t];
        s[t] = (w != 0.0f) ? (-bb / w) : 1e30f;
    }
    __syncthreads();
    for (int k = 2; k <= 128; k <<= 1) {
        for (int j = k >> 1; j > 0; j >>= 1) {
            int ixj = t ^ j;
            if (ixj > t) {
                float a = s[t], bb = s[ixj];
                bool up = ((t & k) == 0);
                if (up ? (a > bb) : (a < bb)) { s[t] = bb; s[ixj] = a; }
            }
            __syncthreads();
        }
    }
    int sg = blockIdx.x;           // 0..128
    float a_rep;
    if (sg == 0)        a_rep = s[0]   - 1.0f;
    else if (sg == 128) a_rep = s[127] + 1.0f;
    else                a_rep = 0.5f * (s[sg - 1] + s[sg]);
    float u = 0.0f, v = 0.0f;
    for (int j = 0; j < 128; ++j) {
        float w = W1[j], bb = b1[j];
        if (a_rep * w + bb > 0.0f) {
            float w2 = W2[j * HIDDEN + t];
            u += w * w2;
            v += bb * w2;
        }
    }
    U[sg * HIDDEN + t] = u;
    V[sg * HIDDEN + t] = v;
}

// ---- conv1 as bucket segment-sum + node info: (c = ns*a, ns, seg, nd)
__global__ __launch_bounds__(256)
void k_conv1_info(const unsigned* __restrict__ bcur1, const unsigned* __restrict__ tmp1,
                  const float* __restrict__ hs0, const unsigned* __restrict__ indeg,
                  const float* __restrict__ ns,
                  const float* __restrict__ W1, const float* __restrict__ b1,
                  float4* __restrict__ info) {
    __shared__ float acc[BSZ];
    __shared__ float sts[128];
    int b = blockIdx.x, t = threadIdx.x;
    if (t < BSZ) acc[t] = 0.0f;
    if (t < 128) {
        float w = W1[t], bb = b1[t];
        sts[t] = (w != 0.0f) ? (-bb / w) : 1e30f;
    }
    __syncthreads();
    for (int k = 2; k <= 128; k <<= 1) {            // bitonic sort sts
        for (int j = k >> 1; j > 0; j >>= 1) {
            if (t < 128) {
                int ixj = t ^ j;
                if (ixj > t) {
                    float a = sts[t], bb = sts[ixj];
                    bool up = ((t & k) == 0);
                    if (up ? (a > bb) : (a < bb)) { sts[t] = bb; sts[ixj] = a; }
                }
            }
            __syncthreads();
        }
    }
    unsigned f1 = min(bcur1[b], (unsigned)CAP);
    const unsigned* tp = tmp1 + (size_t)b * CAP;
    for (unsigned i = t; i < f1; i += 256) {
        unsigned e = tp[i];
        atomicAdd(&acc[e >> 17], hs0[e & 0x1FFFFu]);
    }
    __syncthreads();
    if (t < BSZ) {
        int n = b * BSZ + t;
        if (n < N_NODES) {
            float nd = rsqrtf(fmaxf((float)indeg[n], 1.0f));
            float a  = acc[t] * nd;
            float nsv = ns[n];
            int sg = 0;
            #pragma unroll
            for (int j = 0; j < 128; ++j) sg += (sts[j] < a) ? 1 : 0;
            info[n] = make_float4(nsv * a, nsv, __int_as_float(sg), nd);
        }
    }
}

// ---- conv2 as bucket segment-sum over info + combine + relu + graph pool
__global__ __launch_bounds__(256)
void k_conv2_pool(const unsigned* __restrict__ bcur1, const unsigned* __restrict__ tmp1,
                  const float4* __restrict__ info, const float* __restrict__ U,
                  const float* __restrict__ V, const int* __restrict__ graph_ids,
                  const float* __restrict__ b2,
                  float* __restrict__ pool, float* __restrict__ cnt) {
    __shared__ float sc[BSZ], sn2[BSZ];
    __shared__ uint  smin[BSZ], smax[BSZ];
    __shared__ float sND[BSZ];
    __shared__ int   sGr[BSZ];
    int b = blockIdx.x, t = threadIdx.x;
    if (t < BSZ) { sc[t] = 0.0f; sn2[t] = 0.0f; smin[t] = 255u; smax[t] = 0u; }
    __syncthreads();
    unsigned f1 = min(bcur1[b], (unsigned)CAP);
    const unsigned* tp = tmp1 + (size_t)b * CAP;
    for (unsigned i = t; i < f1; i += 256) {
        unsigned e = tp[i];
        unsigned dl = e >> 17, s = e & 0x1FFFFu;
        float4 nf = info[s];
        uint sg = (uint)__float_as_int(nf.z);
        atomicAdd(&sc[dl],  nf.x);
        atomicAdd(&sn2[dl], nf.y);
        atomicMin(&smin[dl], sg);
        atomicMax(&smax[dl], sg);
    }
    if (t < BSZ) {
        int n = b * BSZ + t;
        if (n < N_NODES) { sND[t] = info[n].w; sGr[t] = graph_ids[n]; }
    }
    __syncthreads();

    // phase 2: 4 waves; wave w handles nodes [w*32, w*32+32), lane covers cols lane & lane+64
    int w = t >> 6, lane = t & 63;
    int base = b * BSZ;
    float bb0 = b2[lane], bb1 = b2[64 + lane];
    int gcur = -1;
    float racc0 = 0.0f, racc1 = 0.0f, cl = 0.0f;

    for (int i = w * 32; i < w * 32 + 32; ++i) {
        int n = base + i;
        if (n >= N_NODES) break;
        float acc0, acc1;
        if (smin[i] >= smax[i]) {                 // uniform segment (or no edges)
            uint sg = (smin[i] <= smax[i]) ? smin[i] : 0u;
            float A = sc[i], B = sn2[i];
            const float* Ur = U + sg * HIDDEN;
            const float* Vr = V + sg * HIDDEN;
            acc0 = A * Ur[lane]      + B * Vr[lane];
            acc1 = A * Ur[64 + lane] + B * Vr[64 + lane];
        } else {                                  // mixed: exact rescan of bucket
            acc0 = 0.0f; acc1 = 0.0f;
            for (unsigned j = 0; j < f1; ++j) {
                unsigned e = tp[j];
                if ((int)(e >> 17) == i) {
                    float4 nf = info[e & 0x1FFFFu];
                    uint sg = (uint)__float_as_int(nf.z);
                    const float* Ur = U + sg * HIDDEN;
                    const float* Vr = V + sg * HIDDEN;
                    acc0 += nf.x * Ur[lane]      + nf.y * Vr[lane];
                    acc1 += nf.x * Ur[64 + lane] + nf.y * Vr[64 + lane];
                }
            }
        }
        float nd = sND[i];
        float r0 = fmaxf(nd * acc0 + bb0, 0.0f);
        float r1 = fmaxf(nd * acc1 + bb1, 0.0f);
        int g = sGr[i];
        if (g != gcur) {
            if (gcur >= 0) {
                atomicAdd(&pool[gcur * HIDDEN + lane],      racc0);
                atomicAdd(&pool[gcur * HIDDEN + 64 + lane], racc1);
                if (lane == 0) atomicAdd(&cnt[gcur], cl);
            }
            gcur = g; racc0 = 0.0f; racc1 = 0.0f; cl = 0.0f;
        }
        racc0 += r0; racc1 += r1; cl += 1.0f;
    }
    if (gcur >= 0) {
        atomicAdd(&pool[gcur * HIDDEN + lane],      racc0);
        atomicAdd(&pool[gcur * HIDDEN + 64 + lane], racc1);
        if (lane == 0) atomicAdd(&cnt[gcur], cl);
    }
}

// ----------------------------------------------- classifier head (tiny)
__global__ void k_final(const float* __restrict__ pool, const float* __restrict__ cnt,
                        const float* __restrict__ Wc, const float* __restrict__ bc,
                        float* __restrict__ out) {
    int t = blockIdx.x * blockDim.x + threadIdx.x;
    if (t >= N_GRAPHS * N_CLASSES) return;
    int g = t / N_CLASSES, c = t % N_CLASSES;
    float inv = 1.0f / fmaxf(cnt[g], 1.0f);
    float acc = bc[c];
    for (int j = 0; j < HIDDEN; ++j)
        acc += pool[g * HIDDEN + j] * inv * Wc[j * N_CLASSES + c];
    out[t] = acc;
}

extern "C" void kernel_launch(void* const* d_in, const int* in_sizes, int n_in,
                              void* d_out, int out_size, void* d_ws, size_t ws_size,
                              hipStream_t stream) {
    const int*   src       = (const int*)d_in[0];
    const int*   dst       = (const int*)d_in[1];
    const int*   graph_ids = (const int*)d_in[2];
    const float* W1        = (const float*)d_in[3];
    const float* b1        = (const float*)d_in[4];
    const float* W2        = (const float*)d_in[5];
    const float* b2        = (const float*)d_in[6];
    const float* Wc        = (const float*)d_in[7];
    const float* bc        = (const float*)d_in[8];
    float* out = (float*)d_out;

    char* ws = (char*)d_ws;
    size_t off = 0;
    auto alloc = [&](size_t elems) { void* p = ws + off; off += elems * 4; return p; };

    // --- zeroed region (one tiny memset ~72 KB); size is 16B-multiple ---
    unsigned* bcur1 = (unsigned*)alloc(NBF);                 // 782
    unsigned* bcur2 = (unsigned*)alloc(NBF + 2);             // pad to keep 16B alignment
    float*    pool  = (float*)   alloc(N_GRAPHS * HIDDEN);
    float*    cnt   = (float*)   alloc(N_GRAPHS);
    size_t zero_bytes = off;                                 // (782+784+16384+128)*4 = 72312... ensure /16
    // pad zero region to 16
    while (zero_bytes % 16) { alloc(1); zero_bytes = off; }
    // --- non-zeroed ---
    float4*   info  = (float4*)  alloc((size_t)N_NODES * 4); // 1.6 MB (16B-aligned)
    unsigned* tmp1  = (unsigned*)alloc((size_t)NBF * CAP);   // 8.0 MB
    uchar*    tmp2  = (uchar*)   alloc(((size_t)NBF * CAP + 3) / 4);  // 2.0 MB
    unsigned* indeg = (unsigned*)alloc(N_NODES);
    float*    nsA   = (float*)   alloc(N_NODES);
    float*    hs0   = (float*)   alloc(N_NODES);
    float*    U     = (float*)   alloc(129 * HIDDEN);
    float*    V     = (float*)   alloc(129 * HIDDEN);

    hipMemsetAsync(d_ws, 0, zero_bytes, stream);

    int pblocks = (N_EDGES + PCH - 1) / PCH;   // 391
    k_part_dst  <<<pblocks, 256, 0, stream>>>(src, dst, bcur1, tmp1, N_EDGES);
    k_part_src  <<<pblocks, 256, 0, stream>>>(src, bcur2, tmp2, N_EDGES);
    k_ind_odeg  <<<NBF, 256, 0, stream>>>(bcur1, tmp1, bcur2, tmp2, indeg, nsA, hs0);
    k_segtable  <<<129, 128, 0, stream>>>(W1, b1, W2, U, V);
    k_conv1_info<<<NBF, 256, 0, stream>>>(bcur1, tmp1, hs0, indeg, nsA, W1, b1, info);
    k_conv2_pool<<<NBF, 256, 0, stream>>>(bcur1, tmp1, info, U, V, graph_ids, b2, pool, cnt);
    k_final     <<<(N_GRAPHS * N_CLASSES + 255) / 256, 256, 0, stream>>>(pool, cnt, Wc, bc, out);
}

// Round 9
// 219.382 us; speedup vs baseline: 1.2065x; 1.2065x over previous
//
#include <hip/hip_runtime.h>

#define N_NODES   100000
#define N_EDGES   1600000
#define N_GRAPHS  128
#define HIDDEN    128
#define N_CLASSES 10

#define BSH   9                   // bucket = 512 nodes (partition-friendly)
#define BSZ   512
#define NBUCK 196                 // ceil(100000/512)
#define CAP   16384               // mean fill 8192, sigma ~90
#define PCH   4096                // edges per partition block

typedef unsigned int   uint;
typedef unsigned short ushort;
typedef unsigned char  uchar;

// ---------------- partition edges by dst>>9; payload = (dst&511)<<17 | src
__global__ __launch_bounds__(256)
void k_part_dst(const int* __restrict__ src, const int* __restrict__ dst,
                unsigned* __restrict__ bcur, unsigned* __restrict__ tmp, int nE) {
    __shared__ unsigned hist[256];
    __shared__ unsigned scan[256];
    __shared__ unsigned lcur[256];
    __shared__ unsigned base[256];
    __shared__ unsigned stag[PCH];
    __shared__ uchar    stagB[PCH];
    int t = threadIdx.x;
    int e0 = blockIdx.x * PCH;
    int e1 = min(e0 + PCH, nE);
    hist[t] = 0;
    __syncthreads();
    for (int e = e0 + t; e < e1; e += 256)
        atomicAdd(&hist[dst[e] >> BSH], 1u);
    __syncthreads();
    unsigned v = hist[t];
    scan[t] = v; __syncthreads();
    for (int off = 1; off < 256; off <<= 1) {
        unsigned add = (t >= off) ? scan[t - off] : 0u;
        __syncthreads();
        scan[t] += add;
        __syncthreads();
    }
    unsigned excl = scan[t] - v;
    if (v > 0) {
        unsigned g = atomicAdd(&bcur[t], v);
        base[t] = (unsigned)t * CAP + g - excl;   // modular wrap cancels on +i
    }
    lcur[t] = excl;
    __syncthreads();
    for (int e = e0 + t; e < e1; e += 256) {
        int d = dst[e], b = d >> BSH;
        unsigned p = atomicAdd(&lcur[b], 1u);
        stag[p]  = ((unsigned)(d & (BSZ - 1)) << 17) | (unsigned)src[e];
        stagB[p] = (uchar)b;
    }
    __syncthreads();
    int cnt = e1 - e0;
    for (int i = t; i < cnt; i += 256) {
        unsigned b = stagB[i];
        unsigned a = base[b] + (unsigned)i;
        if (a < (b + 1u) * CAP) tmp[a] = stag[i];
    }
}

// ---------------- partition by src>>9; payload = src&511 (ushort, for outdeg)
__global__ __launch_bounds__(256)
void k_part_src(const int* __restrict__ src,
                unsigned* __restrict__ bcur, ushort* __restrict__ tmp, int nE) {
    __shared__ unsigned hist[256];
    __shared__ unsigned scan[256];
    __shared__ unsigned lcur[256];
    __shared__ unsigned base[256];
    __shared__ ushort   stag[PCH];
    __shared__ uchar    stagB[PCH];
    int t = threadIdx.x;
    int e0 = blockIdx.x * PCH;
    int e1 = min(e0 + PCH, nE);
    hist[t] = 0;
    __syncthreads();
    for (int e = e0 + t; e < e1; e += 256)
        atomicAdd(&hist[src[e] >> BSH], 1u);
    __syncthreads();
    unsigned v = hist[t];
    scan[t] = v; __syncthreads();
    for (int off = 1; off < 256; off <<= 1) {
        unsigned add = (t >= off) ? scan[t - off] : 0u;
        __syncthreads();
        scan[t] += add;
        __syncthreads();
    }
    unsigned excl = scan[t] - v;
    if (v > 0) {
        unsigned g = atomicAdd(&bcur[t], v);
        base[t] = (unsigned)t * CAP + g - excl;
    }
    lcur[t] = excl;
    __syncthreads();
    for (int e = e0 + t; e < e1; e += 256) {
        int s = src[e], b = s >> BSH;
        unsigned p = atomicAdd(&lcur[b], 1u);
        stag[p]  = (ushort)(s & (BSZ - 1));
        stagB[p] = (uchar)b;
    }
    __syncthreads();
    int cnt = e1 - e0;
    for (int i = t; i < cnt; i += 256) {
        unsigned b = stagB[i];
        unsigned a = base[b] + (unsigned)i;
        if (a < (b + 1u) * CAP) tmp[a] = stag[i];
    }
}

// ------- per bucket (512 threads): indeg + outdeg + ns + hs0 in one scan
__global__ __launch_bounds__(512)
void k_ind_hs0(const unsigned* __restrict__ bcur1, const unsigned* __restrict__ tmp1,
               const unsigned* __restrict__ bcur2, const ushort* __restrict__ tmp2,
               unsigned* __restrict__ indeg, float* __restrict__ ns,
               float* __restrict__ hs0) {
    __shared__ unsigned cin[BSZ], cout[BSZ];
    int b = blockIdx.x, t = threadIdx.x;
    cin[t] = 0; cout[t] = 0;
    __syncthreads();
    unsigned f1 = min(bcur1[b], (unsigned)CAP);
    const unsigned* tp1 = tmp1 + (size_t)b * CAP;
    for (unsigned i = t; i < f1; i += 512) atomicAdd(&cin[tp1[i] >> 17], 1u);
    unsigned f2 = min(bcur2[b], (unsigned)CAP);
    const ushort* tp2 = tmp2 + (size_t)b * CAP;
    for (unsigned i = t; i < f2; i += 512) atomicAdd(&cout[tp2[i]], 1u);
    __syncthreads();
    int n = b * BSZ + t;
    if (n < N_NODES) {
        unsigned ci = cin[t], co = cout[t];
        float nsv = rsqrtf(fmaxf((float)co, 1.0f));
        indeg[n] = ci;
        ns[n]    = nsv;
        hs0[n]   = (float)ci * nsv;
    }
}

// ---- segment table: block self-sorts breakpoints, computes its row
//      U_s = (W1.m_s)@W2, V_s = (b1.m_s)@W2
__global__ void k_segtable(const float* __restrict__ W1, const float* __restrict__ b1,
                           const float* __restrict__ W2,
                           float* __restrict__ U, float* __restrict__ V) {
    __shared__ float s[128];
    int t = threadIdx.x;           // 128 threads
    {
        float w = W1[t], bb = b1[t];
        s[t] = (w != 0.0f) ? (-bb / w) : 1e30f;
    }
    __syncthreads();
    for (int k = 2; k <= 128; k <<= 1) {
        for (int j = k >> 1; j > 0; j >>= 1) {
            int ixj = t ^ j;
            if (ixj > t) {
                float a = s[t], bb = s[ixj];
                bool up = ((t & k) == 0);
                if (up ? (a > bb) : (a < bb)) { s[t] = bb; s[ixj] = a; }
            }
            __syncthreads();
        }
    }
    int sg = blockIdx.x;           // 0..128
    float a_rep;
    if (sg == 0)        a_rep = s[0]   - 1.0f;
    else if (sg == 128) a_rep = s[127] + 1.0f;
    else                a_rep = 0.5f * (s[sg - 1] + s[sg]);
    float u = 0.0f, v = 0.0f;
    for (int j = 0; j < 128; ++j) {
        float w = W1[j], bb = b1[j];
        if (a_rep * w + bb > 0.0f) {
            float w2 = W2[j * HIDDEN + t];
            u += w * w2;
            v += bb * w2;
        }
    }
    U[sg * HIDDEN + t] = u;
    V[sg * HIDDEN + t] = v;
}

// ---- conv1 as bucket segment-sum (512 threads) + node info (c, ns, seg, nd)
__global__ __launch_bounds__(512)
void k_conv1_info(const unsigned* __restrict__ bcur1, const unsigned* __restrict__ tmp1,
                  const float* __restrict__ hs0, const unsigned* __restrict__ indeg,
                  const float* __restrict__ ns,
                  const float* __restrict__ W1, const float* __restrict__ b1,
                  float4* __restrict__ info) {
    __shared__ float acc[BSZ];
    __shared__ float sts[128];
    int b = blockIdx.x, t = threadIdx.x;
    acc[t] = 0.0f;
    if (t < 128) {
        float w = W1[t], bb = b1[t];
        sts[t] = (w != 0.0f) ? (-bb / w) : 1e30f;
    }
    __syncthreads();
    for (int k = 2; k <= 128; k <<= 1) {            // bitonic sort sts
        for (int j = k >> 1; j > 0; j >>= 1) {
            if (t < 128) {
                int ixj = t ^ j;
                if (ixj > t) {
                    float a = sts[t], bb = sts[ixj];
                    bool up = ((t & k) == 0);
                    if (up ? (a > bb) : (a < bb)) { sts[t] = bb; sts[ixj] = a; }
                }
            }
            __syncthreads();
        }
    }
    unsigned f1 = min(bcur1[b], (unsigned)CAP);
    const unsigned* tp = tmp1 + (size_t)b * CAP;
    for (unsigned i = t; i < f1; i += 512) {
        unsigned e = tp[i];
        atomicAdd(&acc[e >> 17], hs0[e & 0x1FFFFu]);
    }
    __syncthreads();
    int n = b * BSZ + t;
    if (n < N_NODES) {
        float nd = rsqrtf(fmaxf((float)indeg[n], 1.0f));
        float a  = acc[t] * nd;
        float nsv = ns[n];
        int sg = 0;
        #pragma unroll
        for (int j = 0; j < 128; ++j) sg += (sts[j] < a) ? 1 : 0;
        info[n] = make_float4(nsv * a, nsv, __int_as_float(sg), nd);
    }
}

// ---- conv2 as bucket segment-sum (512 threads) + combine + relu + graph pool
__global__ __launch_bounds__(512)
void k_conv2_pool(const unsigned* __restrict__ bcur1, const unsigned* __restrict__ tmp1,
                  const float4* __restrict__ info, const float* __restrict__ U,
                  const float* __restrict__ V, const int* __restrict__ graph_ids,
                  const float* __restrict__ b2,
                  float* __restrict__ pool, float* __restrict__ cnt) {
    __shared__ float sc[BSZ], sn2[BSZ];
    __shared__ uint  smin[BSZ], smax[BSZ];
    __shared__ float sND[BSZ];
    __shared__ int   sGr[BSZ];
    int b = blockIdx.x, t = threadIdx.x;
    sc[t] = 0.0f; sn2[t] = 0.0f; smin[t] = 255u; smax[t] = 0u;
    __syncthreads();
    unsigned f1 = min(bcur1[b], (unsigned)CAP);
    const unsigned* tp = tmp1 + (size_t)b * CAP;
    for (unsigned i = t; i < f1; i += 512) {
        unsigned e = tp[i];
        unsigned dl = e >> 17, s = e & 0x1FFFFu;
        float4 nf = info[s];
        uint sg = (uint)__float_as_int(nf.z);
        atomicAdd(&sc[dl],  nf.x);
        atomicAdd(&sn2[dl], nf.y);
        atomicMin(&smin[dl], sg);
        atomicMax(&smax[dl], sg);
    }
    {
        int n = b * BSZ + t;
        if (n < N_NODES) { sND[t] = info[n].w; sGr[t] = graph_ids[n]; }
    }
    __syncthreads();

    // phase 2: 8 waves; wave w handles nodes [w*64, w*64+64)
    int w = t >> 6, lane = t & 63;
    int base = b * BSZ;
    float bb0 = b2[lane], bb1 = b2[64 + lane];
    int gcur = -1;
    float racc0 = 0.0f, racc1 = 0.0f, cl = 0.0f;

    for (int i = w * 64; i < w * 64 + 64; ++i) {
        int n = base + i;
        if (n >= N_NODES) break;
        float acc0, acc1;
        if (smin[i] >= smax[i]) {                 // uniform segment (or no edges)
            uint sg = (smin[i] <= smax[i]) ? smin[i] : 0u;
            float A = sc[i], B = sn2[i];
            const float* Ur = U + sg * HIDDEN;
            const float* Vr = V + sg * HIDDEN;
            acc0 = A * Ur[lane]      + B * Vr[lane];
            acc1 = A * Ur[64 + lane] + B * Vr[64 + lane];
        } else {                                  // mixed: exact rescan of bucket
            acc0 = 0.0f; acc1 = 0.0f;
            for (unsigned j = 0; j < f1; ++j) {
                unsigned e = tp[j];
                if ((int)(e >> 17) == i) {
                    float4 nf = info[e & 0x1FFFFu];
                    uint sg = (uint)__float_as_int(nf.z);
                    const float* Ur = U + sg * HIDDEN;
                    const float* Vr = V + sg * HIDDEN;
                    acc0 += nf.x * Ur[lane]      + nf.y * Vr[lane];
                    acc1 += nf.x * Ur[64 + lane] + nf.y * Vr[64 + lane];
                }
            }
        }
        float nd = sND[i];
        float r0 = fmaxf(nd * acc0 + bb0, 0.0f);
        float r1 = fmaxf(nd * acc1 + bb1, 0.0f);
        int g = sGr[i];
        if (g != gcur) {
            if (gcur >= 0) {
                atomicAdd(&pool[gcur * HIDDEN + lane],      racc0);
                atomicAdd(&pool[gcur * HIDDEN + 64 + lane], racc1);
                if (lane == 0) atomicAdd(&cnt[gcur], cl);
            }
            gcur = g; racc0 = 0.0f; racc1 = 0.0f; cl = 0.0f;
        }
        racc0 += r0; racc1 += r1; cl += 1.0f;
    }
    if (gcur >= 0) {
        atomicAdd(&pool[gcur * HIDDEN + lane],      racc0);
        atomicAdd(&pool[gcur * HIDDEN + 64 + lane], racc1);
        if (lane == 0) atomicAdd(&cnt[gcur], cl);
    }
}

// ----------------------------------------------- classifier head (tiny)
__global__ void k_final(const float* __restrict__ pool, const float* __restrict__ cnt,
                        const float* __restrict__ Wc, const float* __restrict__ bc,
                        float* __restrict__ out) {
    int t = blockIdx.x * blockDim.x + threadIdx.x;
    if (t >= N_GRAPHS * N_CLASSES) return;
    int g = t / N_CLASSES, c = t % N_CLASSES;
    float inv = 1.0f / fmaxf(cnt[g], 1.0f);
    float acc = bc[c];
    for (int j = 0; j < HIDDEN; ++j)
        acc += pool[g * HIDDEN + j] * inv * Wc[j * N_CLASSES + c];
    out[t] = acc;
}

extern "C" void kernel_launch(void* const* d_in, const int* in_sizes, int n_in,
                              void* d_out, int out_size, void* d_ws, size_t ws_size,
                              hipStream_t stream) {
    const int*   src       = (const int*)d_in[0];
    const int*   dst       = (const int*)d_in[1];
    const int*   graph_ids = (const int*)d_in[2];
    const float* W1        = (const float*)d_in[3];
    const float* b1        = (const float*)d_in[4];
    const float* W2        = (const float*)d_in[5];
    const float* b2        = (const float*)d_in[6];
    const float* Wc        = (const float*)d_in[7];
    const float* bc        = (const float*)d_in[8];
    float* out = (float*)d_out;

    char* ws = (char*)d_ws;
    size_t off = 0;
    auto alloc = [&](size_t elems) { void* p = ws + off; off += elems * 4; return p; };

    // --- zeroed region (one tiny memset, 68096 B, 16B-multiple) ---
    unsigned* bcur1 = (unsigned*)alloc(256);
    unsigned* bcur2 = (unsigned*)alloc(256);
    float*    pool  = (float*)   alloc(N_GRAPHS * HIDDEN);
    float*    cnt   = (float*)   alloc(N_GRAPHS);
    size_t zero_bytes = off;
    // --- non-zeroed ---
    float4*   info  = (float4*)  alloc((size_t)N_NODES * 4);        // 1.6 MB
    unsigned* tmp1  = (unsigned*)alloc((size_t)NBUCK * CAP);        // 12.8 MB
    ushort*   tmp2  = (ushort*)  alloc((size_t)NBUCK * CAP / 2);    // 6.4 MB
    unsigned* indeg = (unsigned*)alloc(N_NODES);
    float*    nsA   = (float*)   alloc(N_NODES);
    float*    hs0   = (float*)   alloc(N_NODES);
    float*    U     = (float*)   alloc(129 * HIDDEN);
    float*    V     = (float*)   alloc(129 * HIDDEN);

    hipMemsetAsync(d_ws, 0, zero_bytes, stream);

    int pblocks = (N_EDGES + PCH - 1) / PCH;   // 391
    k_part_dst  <<<pblocks, 256, 0, stream>>>(src, dst, bcur1, tmp1, N_EDGES);
    k_part_src  <<<pblocks, 256, 0, stream>>>(src, bcur2, tmp2, N_EDGES);
    k_ind_hs0   <<<NBUCK, 512, 0, stream>>>(bcur1, tmp1, bcur2, tmp2, indeg, nsA, hs0);
    k_segtable  <<<129, 128, 0, stream>>>(W1, b1, W2, U, V);
    k_conv1_info<<<NBUCK, 512, 0, stream>>>(bcur1, tmp1, hs0, indeg, nsA, W1, b1, info);
    k_conv2_pool<<<NBUCK, 512, 0, stream>>>(bcur1, tmp1, info, U, V, graph_ids, b2, pool, cnt);
    k_final     <<<(N_GRAPHS * N_CLASSES + 255) / 256, 256, 0, stream>>>(pool, cnt, Wc, bc, out);
}

// Round 10
// 201.286 us; speedup vs baseline: 1.3150x; 1.0899x over previous
//
#include <hip/hip_runtime.h>

#define N_NODES   100000
#define N_EDGES   1600000
#define N_GRAPHS  128
#define HIDDEN    128
#define N_CLASSES 10

#define BSH   9                   // bucket = 512 nodes (partition-friendly)
#define BSZ   512
#define NBUCK 196                 // ceil(100000/512)
#define CAP   16384               // mean fill 8192, sigma ~90
#define PCH   4096                // edges per partition block

typedef unsigned int   uint;
typedef unsigned short ushort;
typedef unsigned char  uchar;
typedef unsigned long long ull;

// -------- fused partition: dst-partition (tmp1) + src-partition (tmp2), one edge pass
__global__ __launch_bounds__(256)
void k_part(const int* __restrict__ src, const int* __restrict__ dst,
            unsigned* __restrict__ bcur1, unsigned* __restrict__ bcur2,
            unsigned* __restrict__ tmp1, ushort* __restrict__ tmp2, int nE) {
    __shared__ unsigned histD[256], histS[256], scanT[256];
    __shared__ unsigned lcurD[256], lcurS[256], baseD[256], baseS[256];
    __shared__ unsigned stag1[PCH];
    __shared__ ushort   stag2[PCH];
    __shared__ uchar    stagB1[PCH], stagB2[PCH];
    int t = threadIdx.x;
    int e0 = blockIdx.x * PCH;
    int e1 = min(e0 + PCH, nE);
    histD[t] = 0; histS[t] = 0;
    __syncthreads();
    for (int e = e0 + t; e < e1; e += 256) {
        atomicAdd(&histD[dst[e] >> BSH], 1u);
        atomicAdd(&histS[src[e] >> BSH], 1u);
    }
    __syncthreads();
    // scan + reserve (dst)
    unsigned vD = histD[t];
    scanT[t] = vD; __syncthreads();
    for (int off = 1; off < 256; off <<= 1) {
        unsigned add = (t >= off) ? scanT[t - off] : 0u;
        __syncthreads();
        scanT[t] += add;
        __syncthreads();
    }
    unsigned exD = scanT[t] - vD;
    if (vD > 0) { unsigned g = atomicAdd(&bcur1[t], vD); baseD[t] = (unsigned)t * CAP + g - exD; }
    lcurD[t] = exD;
    __syncthreads();
    // scan + reserve (src)
    unsigned vS = histS[t];
    scanT[t] = vS; __syncthreads();
    for (int off = 1; off < 256; off <<= 1) {
        unsigned add = (t >= off) ? scanT[t - off] : 0u;
        __syncthreads();
        scanT[t] += add;
        __syncthreads();
    }
    unsigned exS = scanT[t] - vS;
    if (vS > 0) { unsigned g = atomicAdd(&bcur2[t], vS); baseS[t] = (unsigned)t * CAP + g - exS; }
    lcurS[t] = exS;
    __syncthreads();
    // scatter both into LDS staging
    for (int e = e0 + t; e < e1; e += 256) {
        int d = dst[e], s = src[e];
        int bd = d >> BSH, bs = s >> BSH;
        unsigned p1 = atomicAdd(&lcurD[bd], 1u);
        stag1[p1]  = ((unsigned)(d & (BSZ - 1)) << 17) | (unsigned)s;
        stagB1[p1] = (uchar)bd;
        unsigned p2 = atomicAdd(&lcurS[bs], 1u);
        stag2[p2]  = (ushort)(s & (BSZ - 1));
        stagB2[p2] = (uchar)bs;
    }
    __syncthreads();
    int cntE = e1 - e0;
    for (int i = t; i < cntE; i += 256) {
        unsigned b = stagB1[i];
        unsigned a = baseD[b] + (unsigned)i;
        if (a < (b + 1u) * CAP) tmp1[a] = stag1[i];
    }
    for (int i = t; i < cntE; i += 256) {
        unsigned b = stagB2[i];
        unsigned a = baseS[b] + (unsigned)i;
        if (a < (b + 1u) * CAP) tmp2[a] = stag2[i];
    }
}

// ------- per bucket (1024 threads): indeg + outdeg + ns + hs0 in one scan
__global__ __launch_bounds__(1024)
void k_ind_hs0(const unsigned* __restrict__ bcur1, const unsigned* __restrict__ tmp1,
               const unsigned* __restrict__ bcur2, const ushort* __restrict__ tmp2,
               unsigned* __restrict__ indeg, float* __restrict__ ns,
               float* __restrict__ hs0) {
    __shared__ unsigned cin[BSZ], cout[BSZ];
    int b = blockIdx.x, t = threadIdx.x;
    if (t < BSZ) { cin[t] = 0; cout[t] = 0; }
    __syncthreads();
    unsigned f1 = min(bcur1[b], (unsigned)CAP);
    const unsigned* tp1 = tmp1 + (size_t)b * CAP;
    for (unsigned i = t; i < f1; i += 1024) atomicAdd(&cin[tp1[i] >> 17], 1u);
    unsigned f2 = min(bcur2[b], (unsigned)CAP);
    const ushort* tp2 = tmp2 + (size_t)b * CAP;
    for (unsigned i = t; i < f2; i += 1024) atomicAdd(&cout[tp2[i]], 1u);
    __syncthreads();
    if (t < BSZ) {
        int n = b * BSZ + t;
        if (n < N_NODES) {
            unsigned ci = cin[t], co = cout[t];
            float nsv = rsqrtf(fmaxf((float)co, 1.0f));
            indeg[n] = ci;
            ns[n]    = nsv;
            hs0[n]   = (float)ci * nsv;
        }
    }
}

// ---- segment table: block self-sorts breakpoints, computes its row; block 0
//      also exports the sorted breakpoints.  U_s = (W1.m_s)@W2, V_s = (b1.m_s)@W2
__global__ void k_segtable(const float* __restrict__ W1, const float* __restrict__ b1,
                           const float* __restrict__ W2,
                           float* __restrict__ U, float* __restrict__ V,
                           float* __restrict__ ts) {
    __shared__ float s[128];
    int t = threadIdx.x;           // 128 threads
    {
        float w = W1[t], bb = b1[t];
        s[t] = (w != 0.0f) ? (-bb / w) : 1e30f;
    }
    __syncthreads();
    for (int k = 2; k <= 128; k <<= 1) {
        for (int j = k >> 1; j > 0; j >>= 1) {
            int ixj = t ^ j;
            if (ixj > t) {
                float a = s[t], bb = s[ixj];
                bool up = ((t & k) == 0);
                if (up ? (a > bb) : (a < bb)) { s[t] = bb; s[ixj] = a; }
            }
            __syncthreads();
        }
    }
    if (blockIdx.x == 0) ts[t] = s[t];
    int sg = blockIdx.x;           // 0..128
    float a_rep;
    if (sg == 0)        a_rep = s[0]   - 1.0f;
    else if (sg == 128) a_rep = s[127] + 1.0f;
    else                a_rep = 0.5f * (s[sg - 1] + s[sg]);
    float u = 0.0f, v = 0.0f;
    for (int j = 0; j < 128; ++j) {
        float w = W1[j], bb = b1[j];
        if (a_rep * w + bb > 0.0f) {
            float w2 = W2[j * HIDDEN + t];
            u += w * w2;
            v += bb * w2;
        }
    }
    U[sg * HIDDEN + t] = u;
    V[sg * HIDDEN + t] = v;
}

// ---- conv1 as bucket segment-sum (1024 threads) + node info (c, ns, seg, nd)
__global__ __launch_bounds__(1024)
void k_conv1_info(const unsigned* __restrict__ bcur1, const unsigned* __restrict__ tmp1,
                  const float* __restrict__ hs0, const unsigned* __restrict__ indeg,
                  const float* __restrict__ ns, const float* __restrict__ ts,
                  float4* __restrict__ info) {
    __shared__ float acc[BSZ];
    __shared__ float sts[128];
    int b = blockIdx.x, t = threadIdx.x;
    if (t < BSZ) acc[t] = 0.0f;
    if (t < 128) sts[t] = ts[t];
    __syncthreads();
    unsigned f1 = min(bcur1[b], (unsigned)CAP);
    const unsigned* tp = tmp1 + (size_t)b * CAP;
    for (unsigned i = t; i < f1; i += 1024) {
        unsigned e = tp[i];
        atomicAdd(&acc[e >> 17], hs0[e & 0x1FFFFu]);
    }
    __syncthreads();
    if (t < BSZ) {
        int n = b * BSZ + t;
        if (n < N_NODES) {
            float nd = rsqrtf(fmaxf((float)indeg[n], 1.0f));
            float a  = acc[t] * nd;
            float nsv = ns[n];
            int sg = 0;
            #pragma unroll
            for (int j = 0; j < 128; ++j) sg += (sts[j] < a) ? 1 : 0;
            info[n] = make_float4(nsv * a, nsv, __int_as_float(sg), nd);
        }
    }
}

// ---- conv2 as bucket segment-sum (1024 threads) + combine + relu + graph pool
//      uniformity via 64-bit packed (sum sg^2 | sum sg): uniform iff n*S2 == S1^2
__global__ __launch_bounds__(1024)
void k_conv2_pool(const unsigned* __restrict__ bcur1, const unsigned* __restrict__ tmp1,
                  const float4* __restrict__ info, const unsigned* __restrict__ indeg,
                  const float* __restrict__ U, const float* __restrict__ V,
                  const int* __restrict__ graph_ids, const float* __restrict__ b2,
                  float* __restrict__ pool, float* __restrict__ cnt) {
    __shared__ float sc[BSZ], sn2[BSZ];
    __shared__ ull   ssq[BSZ];
    __shared__ float sND[BSZ];
    __shared__ int   sGr[BSZ];
    int b = blockIdx.x, t = threadIdx.x;
    if (t < BSZ) { sc[t] = 0.0f; sn2[t] = 0.0f; ssq[t] = 0ull; }
    __syncthreads();
    unsigned f1 = min(bcur1[b], (unsigned)CAP);
    const unsigned* tp = tmp1 + (size_t)b * CAP;
    for (unsigned i = t; i < f1; i += 1024) {
        unsigned e = tp[i];
        unsigned dl = e >> 17, s = e & 0x1FFFFu;
        float4 nf = info[s];
        unsigned sg = (unsigned)__float_as_int(nf.z);
        atomicAdd(&sc[dl],  nf.x);
        atomicAdd(&sn2[dl], nf.y);
        atomicAdd(&ssq[dl], ((ull)(sg * sg) << 32) | (ull)sg);
    }
    if (t < BSZ) {
        int n = b * BSZ + t;
        if (n < N_NODES) { sND[t] = info[n].w; sGr[t] = graph_ids[n]; }
    }
    __syncthreads();

    // phase 2: 16 waves; wave w handles nodes [w*32, w*32+32)
    int w = t >> 6, lane = t & 63;
    int base = b * BSZ;
    float bb0 = b2[lane], bb1 = b2[64 + lane];
    int gcur = -1;
    float racc0 = 0.0f, racc1 = 0.0f, cl = 0.0f;

    for (int i = w * 32; i < w * 32 + 32; ++i) {
        int n = base + i;
        if (n >= N_NODES) break;
        unsigned cntN = indeg[n];
        ull pk = ssq[i];
        unsigned S1 = (unsigned)pk, S2 = (unsigned)(pk >> 32);
        float acc0, acc1;
        if ((ull)cntN * S2 == (ull)S1 * S1) {       // uniform segment (or no edges)
            unsigned sg = cntN ? (S1 / cntN) : 0u;
            float A = sc[i], B = sn2[i];
            const float* Ur = U + sg * HIDDEN;
            const float* Vr = V + sg * HIDDEN;
            acc0 = A * Ur[lane]      + B * Vr[lane];
            acc1 = A * Ur[64 + lane] + B * Vr[64 + lane];
        } else {                                    // mixed: exact rescan of bucket
            acc0 = 0.0f; acc1 = 0.0f;
            for (unsigned j = 0; j < f1; ++j) {
                unsigned e = tp[j];
                if ((int)(e >> 17) == i) {
                    float4 nf = info[e & 0x1FFFFu];
                    unsigned sg = (unsigned)__float_as_int(nf.z);
                    const float* Ur = U + sg * HIDDEN;
                    const float* Vr = V + sg * HIDDEN;
                    acc0 += nf.x * Ur[lane]      + nf.y * Vr[lane];
                    acc1 += nf.x * Ur[64 + lane] + nf.y * Vr[64 + lane];
                }
            }
        }
        float nd = sND[i];
        float r0 = fmaxf(nd * acc0 + bb0, 0.0f);
        float r1 = fmaxf(nd * acc1 + bb1, 0.0f);
        int g = sGr[i];
        if (g != gcur) {
            if (gcur >= 0) {
                atomicAdd(&pool[gcur * HIDDEN + lane],      racc0);
                atomicAdd(&pool[gcur * HIDDEN + 64 + lane], racc1);
                if (lane == 0) atomicAdd(&cnt[gcur], cl);
            }
            gcur = g; racc0 = 0.0f; racc1 = 0.0f; cl = 0.0f;
        }
        racc0 += r0; racc1 += r1; cl += 1.0f;
    }
    if (gcur >= 0) {
        atomicAdd(&pool[gcur * HIDDEN + lane],      racc0);
        atomicAdd(&pool[gcur * HIDDEN + 64 + lane], racc1);
        if (lane == 0) atomicAdd(&cnt[gcur], cl);
    }
}

// ----------------------------------------------- classifier head (tiny)
__global__ void k_final(const float* __restrict__ pool, const float* __restrict__ cnt,
                        const float* __restrict__ Wc, const float* __restrict__ bc,
                        float* __restrict__ out) {
    int t = blockIdx.x * blockDim.x + threadIdx.x;
    if (t >= N_GRAPHS * N_CLASSES) return;
    int g = t / N_CLASSES, c = t % N_CLASSES;
    float inv = 1.0f / fmaxf(cnt[g], 1.0f);
    float acc = bc[c];
    for (int j = 0; j < HIDDEN; ++j)
        acc += pool[g * HIDDEN + j] * inv * Wc[j * N_CLASSES + c];
    out[t] = acc;
}

extern "C" void kernel_launch(void* const* d_in, const int* in_sizes, int n_in,
                              void* d_out, int out_size, void* d_ws, size_t ws_size,
                              hipStream_t stream) {
    const int*   src       = (const int*)d_in[0];
    const int*   dst       = (const int*)d_in[1];
    const int*   graph_ids = (const int*)d_in[2];
    const float* W1        = (const float*)d_in[3];
    const float* b1        = (const float*)d_in[4];
    const float* W2        = (const float*)d_in[5];
    const float* b2        = (const float*)d_in[6];
    const float* Wc        = (const float*)d_in[7];
    const float* bc        = (const float*)d_in[8];
    float* out = (float*)d_out;

    char* ws = (char*)d_ws;
    size_t off = 0;
    auto alloc = [&](size_t elems) { void* p = ws + off; off += elems * 4; return p; };

    // --- zeroed region (one tiny memset, 68096 B, 16B-multiple) ---
    unsigned* bcur1 = (unsigned*)alloc(256);
    unsigned* bcur2 = (unsigned*)alloc(256);
    float*    pool  = (float*)   alloc(N_GRAPHS * HIDDEN);
    float*    cnt   = (float*)   alloc(N_GRAPHS);
    size_t zero_bytes = off;
    // --- non-zeroed ---
    float4*   info  = (float4*)  alloc((size_t)N_NODES * 4);        // 1.6 MB
    unsigned* tmp1  = (unsigned*)alloc((size_t)NBUCK * CAP);        // 12.8 MB
    ushort*   tmp2  = (ushort*)  alloc((size_t)NBUCK * CAP / 2);    // 6.4 MB
    unsigned* indeg = (unsigned*)alloc(N_NODES);
    float*    nsA   = (float*)   alloc(N_NODES);
    float*    hs0   = (float*)   alloc(N_NODES);
    float*    ts    = (float*)   alloc(128);
    float*    U     = (float*)   alloc(129 * HIDDEN);
    float*    V     = (float*)   alloc(129 * HIDDEN);

    hipMemsetAsync(d_ws, 0, zero_bytes, stream);

    int pblocks = (N_EDGES + PCH - 1) / PCH;   // 391
    k_part      <<<pblocks, 256, 0, stream>>>(src, dst, bcur1, bcur2, tmp1, tmp2, N_EDGES);
    k_ind_hs0   <<<NBUCK, 1024, 0, stream>>>(bcur1, tmp1, bcur2, tmp2, indeg, nsA, hs0);
    k_segtable  <<<129, 128, 0, stream>>>(W1, b1, W2, U, V, ts);
    k_conv1_info<<<NBUCK, 1024, 0, stream>>>(bcur1, tmp1, hs0, indeg, nsA, ts, info);
    k_conv2_pool<<<NBUCK, 1024, 0, stream>>>(bcur1, tmp1, info, indeg, U, V, graph_ids, b2, pool, cnt);
    k_final     <<<(N_GRAPHS * N_CLASSES + 255) / 256, 256, 0, stream>>>(pool, cnt, Wc, bc, out);
}

// Round 11
// 191.245 us; speedup vs baseline: 1.3840x; 1.0525x over previous
//
#include <hip/hip_runtime.h>

#define N_NODES   100000
#define N_EDGES   1600000
#define N_GRAPHS  128
#define HIDDEN    128
#define N_CLASSES 10

#define BSH   9                   // bucket = 512 nodes (partition-friendly)
#define BSZ   512
#define NBUCK 196                 // ceil(100000/512)
#define CAP   16384               // mean fill 8192, sigma ~90
#define PCH   4096                // edges per partition block

typedef unsigned int   uint;
typedef unsigned short ushort;
typedef unsigned char  uchar;

// -------- fused partition: dst-partition (tmp1) + src-partition (tmp2), one edge pass
__global__ __launch_bounds__(256)
void k_part(const int* __restrict__ src, const int* __restrict__ dst,
            unsigned* __restrict__ bcur1, unsigned* __restrict__ bcur2,
            unsigned* __restrict__ tmp1, ushort* __restrict__ tmp2, int nE) {
    __shared__ unsigned histD[256], histS[256], scanT[256];
    __shared__ unsigned lcurD[256], lcurS[256], baseD[256], baseS[256];
    __shared__ unsigned stag1[PCH];
    __shared__ ushort   stag2[PCH];
    __shared__ uchar    stagB1[PCH], stagB2[PCH];
    int t = threadIdx.x;
    int e0 = blockIdx.x * PCH;
    int e1 = min(e0 + PCH, nE);
    histD[t] = 0; histS[t] = 0;
    __syncthreads();
    for (int e = e0 + t; e < e1; e += 256) {
        atomicAdd(&histD[dst[e] >> BSH], 1u);
        atomicAdd(&histS[src[e] >> BSH], 1u);
    }
    __syncthreads();
    unsigned vD = histD[t];
    scanT[t] = vD; __syncthreads();
    for (int off = 1; off < 256; off <<= 1) {
        unsigned add = (t >= off) ? scanT[t - off] : 0u;
        __syncthreads();
        scanT[t] += add;
        __syncthreads();
    }
    unsigned exD = scanT[t] - vD;
    if (vD > 0) { unsigned g = atomicAdd(&bcur1[t], vD); baseD[t] = (unsigned)t * CAP + g - exD; }
    lcurD[t] = exD;
    __syncthreads();
    unsigned vS = histS[t];
    scanT[t] = vS; __syncthreads();
    for (int off = 1; off < 256; off <<= 1) {
        unsigned add = (t >= off) ? scanT[t - off] : 0u;
        __syncthreads();
        scanT[t] += add;
        __syncthreads();
    }
    unsigned exS = scanT[t] - vS;
    if (vS > 0) { unsigned g = atomicAdd(&bcur2[t], vS); baseS[t] = (unsigned)t * CAP + g - exS; }
    lcurS[t] = exS;
    __syncthreads();
    for (int e = e0 + t; e < e1; e += 256) {
        int d = dst[e], s = src[e];
        int bd = d >> BSH, bs = s >> BSH;
        unsigned p1 = atomicAdd(&lcurD[bd], 1u);
        stag1[p1]  = ((unsigned)(d & (BSZ - 1)) << 17) | (unsigned)s;
        stagB1[p1] = (uchar)bd;
        unsigned p2 = atomicAdd(&lcurS[bs], 1u);
        stag2[p2]  = (ushort)(s & (BSZ - 1));
        stagB2[p2] = (uchar)bs;
    }
    __syncthreads();
    int cntE = e1 - e0;
    for (int i = t; i < cntE; i += 256) {
        unsigned b = stagB1[i];
        unsigned a = baseD[b] + (unsigned)i;
        if (a < (b + 1u) * CAP) tmp1[a] = stag1[i];
    }
    for (int i = t; i < cntE; i += 256) {
        unsigned b = stagB2[i];
        unsigned a = baseS[b] + (unsigned)i;
        if (a < (b + 1u) * CAP) tmp2[a] = stag2[i];
    }
}

// ------- per bucket (1024 thr): degrees + ns + hs0 + bucket counting-sort → CSR
__global__ __launch_bounds__(1024)
void k_ind_csr(const unsigned* __restrict__ bcur1, const unsigned* __restrict__ tmp1,
               const unsigned* __restrict__ bcur2, const ushort* __restrict__ tmp2,
               unsigned* __restrict__ indeg, float* __restrict__ ns,
               float* __restrict__ hs0, int* __restrict__ rs,
               int* __restrict__ csr) {
    __shared__ unsigned cin[BSZ], cout[BSZ], pref[BSZ], lcur[BSZ];
    int b = blockIdx.x, t = threadIdx.x;
    if (t < BSZ) { cin[t] = 0; cout[t] = 0; }
    __syncthreads();
    unsigned f1 = min(bcur1[b], (unsigned)CAP);
    const unsigned* tp1 = tmp1 + (size_t)b * CAP;
    for (unsigned i = t; i < f1; i += 1024) atomicAdd(&cin[tp1[i] >> 17], 1u);
    unsigned f2 = min(bcur2[b], (unsigned)CAP);
    const ushort* tp2 = tmp2 + (size_t)b * CAP;
    for (unsigned i = t; i < f2; i += 1024) atomicAdd(&cout[tp2[i]], 1u);
    __syncthreads();
    // Hillis-Steele inclusive scan over 512 bins (all threads hit the syncs)
    unsigned v = (t < BSZ) ? cin[t] : 0u;
    if (t < BSZ) pref[t] = v;
    __syncthreads();
    for (int off = 1; off < BSZ; off <<= 1) {
        unsigned add = (t < BSZ && t >= off) ? pref[t - off] : 0u;
        __syncthreads();
        if (t < BSZ) pref[t] += add;
        __syncthreads();
    }
    if (t < BSZ) {
        unsigned excl = pref[t] - v;
        lcur[t] = excl;
        int n = b * BSZ + t;
        if (n < N_NODES) {
            unsigned ci = cin[t], co = cout[t];
            float nsv = rsqrtf(fmaxf((float)co, 1.0f));
            indeg[n] = ci;
            ns[n]    = nsv;
            hs0[n]   = (float)ci * nsv;
            rs[n]    = (int)(b * CAP + excl);
        }
    }
    __syncthreads();
    // reorder: bucket-local counting-sort scatter (L2-local 64 KB window)
    int* cb = csr + (size_t)b * CAP;
    for (unsigned i = t; i < f1; i += 1024) {
        unsigned e = tp1[i];
        unsigned pos = atomicAdd(&lcur[e >> 17], 1u);
        cb[pos] = (int)(e & 0x1FFFFu);
    }
}

// ---- segment table: block self-sorts breakpoints, computes its row; block 0
//      also exports the sorted breakpoints.  U_s = (W1.m_s)@W2, V_s = (b1.m_s)@W2
__global__ void k_segtable(const float* __restrict__ W1, const float* __restrict__ b1,
                           const float* __restrict__ W2,
                           float* __restrict__ U, float* __restrict__ V,
                           float* __restrict__ ts) {
    __shared__ float s[128];
    int t = threadIdx.x;           // 128 threads
    {
        float w = W1[t], bb = b1[t];
        s[t] = (w != 0.0f) ? (-bb / w) : 1e30f;
    }
    __syncthreads();
    for (int k = 2; k <= 128; k <<= 1) {
        for (int j = k >> 1; j > 0; j >>= 1) {
            int ixj = t ^ j;
            if (ixj > t) {
                float a = s[t], bb = s[ixj];
                bool up = ((t & k) == 0);
                if (up ? (a > bb) : (a < bb)) { s[t] = bb; s[ixj] = a; }
            }
            __syncthreads();
        }
    }
    if (blockIdx.x == 0) ts[t] = s[t];
    int sg = blockIdx.x;           // 0..128
    float a_rep;
    if (sg == 0)        a_rep = s[0]   - 1.0f;
    else if (sg == 128) a_rep = s[127] + 1.0f;
    else                a_rep = 0.5f * (s[sg - 1] + s[sg]);
    float u = 0.0f, v = 0.0f;
    for (int j = 0; j < 128; ++j) {
        float w = W1[j], bb = b1[j];
        if (a_rep * w + bb > 0.0f) {
            float w2 = W2[j * HIDDEN + t];
            u += w * w2;
            v += bb * w2;
        }
    }
    U[sg * HIDDEN + t] = u;
    V[sg * HIDDEN + t] = v;
}

// ---- conv1: thread-per-node CSR gather (no atomics) + node info (c, ns, seg, nd)
__global__ __launch_bounds__(256)
void k_conv1_info(const int* __restrict__ rs, const int* __restrict__ csr,
                  const float* __restrict__ hs0, const unsigned* __restrict__ indeg,
                  const float* __restrict__ ns, const float* __restrict__ ts,
                  float4* __restrict__ info, int nN) {
    __shared__ float sts[128];
    if (threadIdx.x < 128) sts[threadIdx.x] = ts[threadIdx.x];
    __syncthreads();
    int n = blockIdx.x * 256 + threadIdx.x;
    if (n >= nN) return;
    int r0 = rs[n];
    int c  = (int)indeg[n];
    float a = 0.0f;
    #pragma unroll 4
    for (int k = 0; k < c; ++k) a += hs0[csr[r0 + k]];
    float nd = rsqrtf(fmaxf((float)c, 1.0f));
    a *= nd;
    float nsv = ns[n];
    int sg = 0;
    #pragma unroll
    for (int j = 0; j < 128; ++j) sg += (sts[j] < a) ? 1 : 0;
    info[n] = make_float4(nsv * a, nsv, __int_as_float(sg), nd);
}

// ---- conv2: thread-per-node register accumulation (no atomics), then
//      wave combine + relu + graph pool (sorted graph_ids)
__global__ __launch_bounds__(256)
void k_conv2_pool(const int* __restrict__ rs, const int* __restrict__ csr,
                  const float4* __restrict__ info, const unsigned* __restrict__ indeg,
                  const float* __restrict__ U, const float* __restrict__ V,
                  const int* __restrict__ graph_ids, const float* __restrict__ b2,
                  float* __restrict__ pool, float* __restrict__ cnt, int nN) {
    __shared__ float sA[256], sB[256], sND[256];
    __shared__ int   sSg[256], sGr[256], sR[256], sC[256];
    int blockBase = blockIdx.x * 256;
    int t = threadIdx.x;
    int n = blockBase + t;

    if (n < nN) {
        int r0 = rs[n], c = (int)indeg[n];
        float A = 0.0f, B = 0.0f;
        int mn = 255, mx = 0;
        #pragma unroll 4
        for (int k = 0; k < c; ++k) {
            float4 nf = info[csr[r0 + k]];
            int sg = __float_as_int(nf.z);
            A += nf.x; B += nf.y;
            mn = min(mn, sg); mx = max(mx, sg);
        }
        sA[t] = A; sB[t] = B;
        sSg[t] = (mn << 8) | mx;
        sR[t] = r0; sC[t] = c;
        sND[t] = info[n].w;
        sGr[t] = graph_ids[n];
    }
    __syncthreads();

    int w = t >> 6, lane = t & 63;
    int n0 = blockBase + 64 * w;
    if (n0 >= nN) return;
    int n1 = min(n0 + 64, nN);

    float bb0 = b2[lane], bb1 = b2[64 + lane];
    int gcur = -1;
    float racc0 = 0.0f, racc1 = 0.0f, cl = 0.0f;

    for (int node = n0; node < n1; ++node) {
        int i = node - blockBase;
        int pk = sSg[i], mn = pk >> 8, mx = pk & 255;
        float acc0, acc1;
        if (mn >= mx) {                          // uniform segment (or no edges)
            int sg = min(mn, 128);
            float A = sA[i], B = sB[i];
            const float* Ur = U + sg * HIDDEN;
            const float* Vr = V + sg * HIDDEN;
            acc0 = A * Ur[lane]      + B * Vr[lane];
            acc1 = A * Ur[64 + lane] + B * Vr[64 + lane];
        } else {                                 // mixed: exact per-node rescan (rare)
            acc0 = 0.0f; acc1 = 0.0f;
            int r0 = sR[i], c = sC[i];
            for (int k = 0; k < c; ++k) {
                float4 nf = info[csr[r0 + k]];
                int sg = __float_as_int(nf.z);
                const float* Ur = U + sg * HIDDEN;
                const float* Vr = V + sg * HIDDEN;
                acc0 += nf.x * Ur[lane]      + nf.y * Vr[lane];
                acc1 += nf.x * Ur[64 + lane] + nf.y * Vr[64 + lane];
            }
        }
        float nd = sND[i];
        float r0v = fmaxf(nd * acc0 + bb0, 0.0f);
        float r1v = fmaxf(nd * acc1 + bb1, 0.0f);
        int g = sGr[i];
        if (g != gcur) {
            if (gcur >= 0) {
                atomicAdd(&pool[gcur * HIDDEN + lane],      racc0);
                atomicAdd(&pool[gcur * HIDDEN + 64 + lane], racc1);
                if (lane == 0) atomicAdd(&cnt[gcur], cl);
            }
            gcur = g; racc0 = 0.0f; racc1 = 0.0f; cl = 0.0f;
        }
        racc0 += r0v; racc1 += r1v; cl += 1.0f;
    }
    if (gcur >= 0) {
        atomicAdd(&pool[gcur * HIDDEN + lane],      racc0);
        atomicAdd(&pool[gcur * HIDDEN + 64 + lane], racc1);
        if (lane == 0) atomicAdd(&cnt[gcur], cl);
    }
}

// ----------------------------------------------- classifier head (tiny)
__global__ void k_final(const float* __restrict__ pool, const float* __restrict__ cnt,
                        const float* __restrict__ Wc, const float* __restrict__ bc,
                        float* __restrict__ out) {
    int t = blockIdx.x * blockDim.x + threadIdx.x;
    if (t >= N_GRAPHS * N_CLASSES) return;
    int g = t / N_CLASSES, c = t % N_CLASSES;
    float inv = 1.0f / fmaxf(cnt[g], 1.0f);
    float acc = bc[c];
    for (int j = 0; j < HIDDEN; ++j)
        acc += pool[g * HIDDEN + j] * inv * Wc[j * N_CLASSES + c];
    out[t] = acc;
}

extern "C" void kernel_launch(void* const* d_in, const int* in_sizes, int n_in,
                              void* d_out, int out_size, void* d_ws, size_t ws_size,
                              hipStream_t stream) {
    const int*   src       = (const int*)d_in[0];
    const int*   dst       = (const int*)d_in[1];
    const int*   graph_ids = (const int*)d_in[2];
    const float* W1        = (const float*)d_in[3];
    const float* b1        = (const float*)d_in[4];
    const float* W2        = (const float*)d_in[5];
    const float* b2        = (const float*)d_in[6];
    const float* Wc        = (const float*)d_in[7];
    const float* bc        = (const float*)d_in[8];
    float* out = (float*)d_out;

    char* ws = (char*)d_ws;
    size_t off = 0;
    auto alloc = [&](size_t elems) { void* p = ws + off; off += elems * 4; return p; };

    // --- zeroed region (one tiny memset, 16B-multiple) ---
    unsigned* bcur1 = (unsigned*)alloc(256);
    unsigned* bcur2 = (unsigned*)alloc(256);
    float*    pool  = (float*)   alloc(N_GRAPHS * HIDDEN);
    float*    cnt   = (float*)   alloc(N_GRAPHS);
    size_t zero_bytes = off;
    // --- non-zeroed ---
    float4*   info  = (float4*)  alloc((size_t)N_NODES * 4);        // 1.6 MB
    unsigned* tmp1  = (unsigned*)alloc((size_t)NBUCK * CAP);        // 12.8 MB
    ushort*   tmp2  = (ushort*)  alloc((size_t)NBUCK * CAP / 2);    // 6.4 MB
    int*      csr   = (int*)     alloc((size_t)NBUCK * CAP);        // 12.8 MB
    int*      rs    = (int*)     alloc(N_NODES);
    unsigned* indeg = (unsigned*)alloc(N_NODES);
    float*    nsA   = (float*)   alloc(N_NODES);
    float*    hs0   = (float*)   alloc(N_NODES);
    float*    ts    = (float*)   alloc(128);
    float*    U     = (float*)   alloc(129 * HIDDEN);
    float*    V     = (float*)   alloc(129 * HIDDEN);

    hipMemsetAsync(d_ws, 0, zero_bytes, stream);

    int pblocks = (N_EDGES + PCH - 1) / PCH;   // 391
    int nblocks = (N_NODES + 255) / 256;       // 391
    k_part      <<<pblocks, 256, 0, stream>>>(src, dst, bcur1, bcur2, tmp1, tmp2, N_EDGES);
    k_ind_csr   <<<NBUCK, 1024, 0, stream>>>(bcur1, tmp1, bcur2, tmp2, indeg, nsA, hs0, rs, csr);
    k_segtable  <<<129, 128, 0, stream>>>(W1, b1, W2, U, V, ts);
    k_conv1_info<<<nblocks, 256, 0, stream>>>(rs, csr, hs0, indeg, nsA, ts, info, N_NODES);
    k_conv2_pool<<<nblocks, 256, 0, stream>>>(rs, csr, info, indeg, U, V, graph_ids, b2, pool, cnt, N_NODES);
    k_final     <<<(N_GRAPHS * N_CLASSES + 255) / 256, 256, 0, stream>>>(pool, cnt, Wc, bc, out);
}

// Round 12
// 182.858 us; speedup vs baseline: 1.4475x; 1.0459x over previous
//
#include <hip/hip_runtime.h>

#define N_NODES   100000
#define N_EDGES   1600000
#define N_GRAPHS  128
#define HIDDEN    128
#define N_CLASSES 10

#define BSH   9                   // bucket = 512 nodes (partition-friendly)
#define BSZ   512
#define NBUCK 196                 // ceil(100000/512)
#define CAP   16384               // mean fill 8192, sigma ~90
#define PCH   4096                // edges per partition block
#define PTH   512                 // partition threads

typedef unsigned int   uint;
typedef unsigned short ushort;
typedef unsigned char  uchar;

// -------- partition, two sequential phases sharing one 20 KB staging buffer:
//          phase 1: dst-partition -> tmp1 ((dst&511)<<17 | src)
//          phase 2: src-partition -> tmp2 (src&511)
__global__ __launch_bounds__(PTH)
void k_part(const int* __restrict__ src, const int* __restrict__ dst,
            unsigned* __restrict__ bcur1, unsigned* __restrict__ bcur2,
            unsigned* __restrict__ tmp1, ushort* __restrict__ tmp2, int nE) {
    __shared__ unsigned hist[256], scanT[256], lcur[256], base[256];
    __shared__ unsigned stag4[PCH];      // 16 KB; phase 2 reuses as ushort[PCH]
    __shared__ uchar    stagB[PCH];      // 4 KB
    int t = threadIdx.x;
    int e0 = blockIdx.x * PCH;
    int e1 = min(e0 + PCH, nE);
    int cntE = e1 - e0;

    // ---------------- phase 1: dst ----------------
    if (t < 256) hist[t] = 0;
    __syncthreads();
    for (int e = e0 + t; e < e1; e += PTH)
        atomicAdd(&hist[dst[e] >> BSH], 1u);
    __syncthreads();
    unsigned v = (t < 256) ? hist[t] : 0u;
    if (t < 256) scanT[t] = v;
    __syncthreads();
    for (int off = 1; off < 256; off <<= 1) {
        unsigned add = (t < 256 && t >= off) ? scanT[t - off] : 0u;
        __syncthreads();
        if (t < 256) scanT[t] += add;
        __syncthreads();
    }
    if (t < 256) {
        unsigned excl = scanT[t] - v;
        lcur[t] = excl;
        if (v > 0) { unsigned g = atomicAdd(&bcur1[t], v); base[t] = (unsigned)t * CAP + g - excl; }
    }
    __syncthreads();
    for (int e = e0 + t; e < e1; e += PTH) {
        int d = dst[e], s = src[e];
        int b = d >> BSH;
        unsigned p = atomicAdd(&lcur[b], 1u);
        stag4[p] = ((unsigned)(d & (BSZ - 1)) << 17) | (unsigned)s;
        stagB[p] = (uchar)b;
    }
    __syncthreads();
    for (int i = t; i < cntE; i += PTH) {
        unsigned b = stagB[i];
        unsigned a = base[b] + (unsigned)i;
        if (a < (b + 1u) * CAP) tmp1[a] = stag4[i];
    }
    __syncthreads();

    // ---------------- phase 2: src ----------------
    if (t < 256) hist[t] = 0;
    __syncthreads();
    for (int e = e0 + t; e < e1; e += PTH)
        atomicAdd(&hist[src[e] >> BSH], 1u);
    __syncthreads();
    v = (t < 256) ? hist[t] : 0u;
    if (t < 256) scanT[t] = v;
    __syncthreads();
    for (int off = 1; off < 256; off <<= 1) {
        unsigned add = (t < 256 && t >= off) ? scanT[t - off] : 0u;
        __syncthreads();
        if (t < 256) scanT[t] += add;
        __syncthreads();
    }
    if (t < 256) {
        unsigned excl = scanT[t] - v;
        lcur[t] = excl;
        if (v > 0) { unsigned g = atomicAdd(&bcur2[t], v); base[t] = (unsigned)t * CAP + g - excl; }
    }
    __syncthreads();
    ushort* st2 = (ushort*)stag4;
    for (int e = e0 + t; e < e1; e += PTH) {
        int s = src[e];
        int b = s >> BSH;
        unsigned p = atomicAdd(&lcur[b], 1u);
        st2[p]   = (ushort)(s & (BSZ - 1));
        stagB[p] = (uchar)b;
    }
    __syncthreads();
    for (int i = t; i < cntE; i += PTH) {
        unsigned b = stagB[i];
        unsigned a = base[b] + (unsigned)i;
        if (a < (b + 1u) * CAP) tmp2[a] = st2[i];
    }
}

// ------- per bucket (1024 thr): degrees + ns + hs0 + bucket counting-sort → CSR
__global__ __launch_bounds__(1024)
void k_ind_csr(const unsigned* __restrict__ bcur1, const unsigned* __restrict__ tmp1,
               const unsigned* __restrict__ bcur2, const ushort* __restrict__ tmp2,
               unsigned* __restrict__ indeg, float* __restrict__ ns,
               float* __restrict__ hs0, int* __restrict__ rs,
               int* __restrict__ csr) {
    __shared__ unsigned cin[BSZ], cout[BSZ], pref[BSZ], lcur[BSZ];
    int b = blockIdx.x, t = threadIdx.x;
    if (t < BSZ) { cin[t] = 0; cout[t] = 0; }
    __syncthreads();
    unsigned f1 = min(bcur1[b], (unsigned)CAP);
    const unsigned* tp1 = tmp1 + (size_t)b * CAP;
    for (unsigned i = t; i < f1; i += 1024) atomicAdd(&cin[tp1[i] >> 17], 1u);
    unsigned f2 = min(bcur2[b], (unsigned)CAP);
    const ushort* tp2 = tmp2 + (size_t)b * CAP;
    for (unsigned i = t; i < f2; i += 1024) atomicAdd(&cout[tp2[i]], 1u);
    __syncthreads();
    unsigned v = (t < BSZ) ? cin[t] : 0u;
    if (t < BSZ) pref[t] = v;
    __syncthreads();
    for (int off = 1; off < BSZ; off <<= 1) {
        unsigned add = (t < BSZ && t >= off) ? pref[t - off] : 0u;
        __syncthreads();
        if (t < BSZ) pref[t] += add;
        __syncthreads();
    }
    if (t < BSZ) {
        unsigned excl = pref[t] - v;
        lcur[t] = excl;
        int n = b * BSZ + t;
        if (n < N_NODES) {
            unsigned ci = cin[t], co = cout[t];
            float nsv = rsqrtf(fmaxf((float)co, 1.0f));
            indeg[n] = ci;
            ns[n]    = nsv;
            hs0[n]   = (float)ci * nsv;
            rs[n]    = (int)(b * CAP + excl);
        }
    }
    __syncthreads();
    int* cb = csr + (size_t)b * CAP;
    for (unsigned i = t; i < f1; i += 1024) {
        unsigned e = tp1[i];
        unsigned pos = atomicAdd(&lcur[e >> 17], 1u);
        cb[pos] = (int)(e & 0x1FFFFu);
    }
}

// ---- conv1: thread-per-node CSR gather + node info (c, ns, seg, nd).
//      Every block bitonic-sorts the breakpoints; blocks 0..128 also emit
//      their segment-table row U_s=(W1.m_s)@W2, V_s=(b1.m_s)@W2 (used by conv2).
__global__ __launch_bounds__(256)
void k_conv1_info(const int* __restrict__ rs, const int* __restrict__ csr,
                  const float* __restrict__ hs0, const unsigned* __restrict__ indeg,
                  const float* __restrict__ ns,
                  const float* __restrict__ W1, const float* __restrict__ b1,
                  const float* __restrict__ W2,
                  float* __restrict__ U, float* __restrict__ V,
                  float4* __restrict__ info, int nN) {
    __shared__ float sts[128];
    int t = threadIdx.x;
    if (t < 128) {
        float w = W1[t], bb = b1[t];
        sts[t] = (w != 0.0f) ? (-bb / w) : 1e30f;
    }
    __syncthreads();
    for (int k = 2; k <= 128; k <<= 1) {
        for (int j = k >> 1; j > 0; j >>= 1) {
            if (t < 128) {
                int ixj = t ^ j;
                if (ixj > t) {
                    float a = sts[t], bb = sts[ixj];
                    bool up = ((t & k) == 0);
                    if (up ? (a > bb) : (a < bb)) { sts[t] = bb; sts[ixj] = a; }
                }
            }
            __syncthreads();
        }
    }
    // segment-table row (first 129 blocks)
    if (blockIdx.x < 129 && t < 128) {
        int sg = blockIdx.x;
        float a_rep;
        if (sg == 0)        a_rep = sts[0]   - 1.0f;
        else if (sg == 128) a_rep = sts[127] + 1.0f;
        else                a_rep = 0.5f * (sts[sg - 1] + sts[sg]);
        float u = 0.0f, vv = 0.0f;
        for (int j = 0; j < 128; ++j) {
            float w = W1[j], bb = b1[j];
            if (a_rep * w + bb > 0.0f) {
                float w2 = W2[j * HIDDEN + t];
                u  += w * w2;
                vv += bb * w2;
            }
        }
        U[sg * HIDDEN + t] = u;
        V[sg * HIDDEN + t] = vv;
    }
    // per-node info
    int n = blockIdx.x * 256 + t;
    if (n >= nN) return;
    int r0 = rs[n];
    int c  = (int)indeg[n];
    float a = 0.0f;
    #pragma unroll 4
    for (int k = 0; k < c; ++k) a += hs0[csr[r0 + k]];
    float nd = rsqrtf(fmaxf((float)c, 1.0f));
    a *= nd;
    float nsv = ns[n];
    int sg = 0;
    #pragma unroll
    for (int j = 0; j < 128; ++j) sg += (sts[j] < a) ? 1 : 0;
    info[n] = make_float4(nsv * a, nsv, __int_as_float(sg), nd);
}

// ---- conv2: thread-per-node register accumulation (no atomics), then
//      wave combine + relu + graph pool (sorted graph_ids)
__global__ __launch_bounds__(256)
void k_conv2_pool(const int* __restrict__ rs, const int* __restrict__ csr,
                  const float4* __restrict__ info, const unsigned* __restrict__ indeg,
                  const float* __restrict__ U, const float* __restrict__ V,
                  const int* __restrict__ graph_ids, const float* __restrict__ b2,
                  float* __restrict__ pool, float* __restrict__ cnt, int nN) {
    __shared__ float sA[256], sB[256], sND[256];
    __shared__ int   sSg[256], sGr[256], sR[256], sC[256];
    int blockBase = blockIdx.x * 256;
    int t = threadIdx.x;
    int n = blockBase + t;

    if (n < nN) {
        int r0 = rs[n], c = (int)indeg[n];
        float A = 0.0f, B = 0.0f;
        int mn = 255, mx = 0;
        #pragma unroll 4
        for (int k = 0; k < c; ++k) {
            float4 nf = info[csr[r0 + k]];
            int sg = __float_as_int(nf.z);
            A += nf.x; B += nf.y;
            mn = min(mn, sg); mx = max(mx, sg);
        }
        sA[t] = A; sB[t] = B;
        sSg[t] = (mn << 8) | mx;
        sR[t] = r0; sC[t] = c;
        sND[t] = info[n].w;
        sGr[t] = graph_ids[n];
    }
    __syncthreads();

    int w = t >> 6, lane = t & 63;
    int n0 = blockBase + 64 * w;
    if (n0 >= nN) return;
    int n1 = min(n0 + 64, nN);

    float bb0 = b2[lane], bb1 = b2[64 + lane];
    int gcur = -1;
    float racc0 = 0.0f, racc1 = 0.0f, cl = 0.0f;

    for (int node = n0; node < n1; ++node) {
        int i = node - blockBase;
        int pk = sSg[i], mn = pk >> 8, mx = pk & 255;
        float acc0, acc1;
        if (mn >= mx) {                          // uniform segment (or no edges)
            int sg = min(mn, 128);
            float A = sA[i], B = sB[i];
            const float* Ur = U + sg * HIDDEN;
            const float* Vr = V + sg * HIDDEN;
            acc0 = A * Ur[lane]      + B * Vr[lane];
            acc1 = A * Ur[64 + lane] + B * Vr[64 + lane];
        } else {                                 // mixed: exact per-node rescan (rare)
            acc0 = 0.0f; acc1 = 0.0f;
            int r0 = sR[i], c = sC[i];
            for (int k = 0; k < c; ++k) {
                float4 nf = info[csr[r0 + k]];
                int sg = __float_as_int(nf.z);
                const float* Ur = U + sg * HIDDEN;
                const float* Vr = V + sg * HIDDEN;
                acc0 += nf.x * Ur[lane]      + nf.y * Vr[lane];
                acc1 += nf.x * Ur[64 + lane] + nf.y * Vr[64 + lane];
            }
        }
        float nd = sND[i];
        float r0v = fmaxf(nd * acc0 + bb0, 0.0f);
        float r1v = fmaxf(nd * acc1 + bb1, 0.0f);
        int g = sGr[i];
        if (g != gcur) {
            if (gcur >= 0) {
                atomicAdd(&pool[gcur * HIDDEN + lane],      racc0);
                atomicAdd(&pool[gcur * HIDDEN + 64 + lane], racc1);
                if (lane == 0) atomicAdd(&cnt[gcur], cl);
            }
            gcur = g; racc0 = 0.0f; racc1 = 0.0f; cl = 0.0f;
        }
        racc0 += r0v; racc1 += r1v; cl += 1.0f;
    }
    if (gcur >= 0) {
        atomicAdd(&pool[gcur * HIDDEN + lane],      racc0);
        atomicAdd(&pool[gcur * HIDDEN + 64 + lane], racc1);
        if (lane == 0) atomicAdd(&cnt[gcur], cl);
    }
}

// ----------------------------------------------- classifier head (tiny)
__global__ void k_final(const float* __restrict__ pool, const float* __restrict__ cnt,
                        const float* __restrict__ Wc, const float* __restrict__ bc,
                        float* __restrict__ out) {
    int t = blockIdx.x * blockDim.x + threadIdx.x;
    if (t >= N_GRAPHS * N_CLASSES) return;
    int g = t / N_CLASSES, c = t % N_CLASSES;
    float inv = 1.0f / fmaxf(cnt[g], 1.0f);
    float acc = bc[c];
    for (int j = 0; j < HIDDEN; ++j)
        acc += pool[g * HIDDEN + j] * inv * Wc[j * N_CLASSES + c];
    out[t] = acc;
}

extern "C" void kernel_launch(void* const* d_in, const int* in_sizes, int n_in,
                              void* d_out, int out_size, void* d_ws, size_t ws_size,
                              hipStream_t stream) {
    const int*   src       = (const int*)d_in[0];
    const int*   dst       = (const int*)d_in[1];
    const int*   graph_ids = (const int*)d_in[2];
    const float* W1        = (const float*)d_in[3];
    const float* b1        = (const float*)d_in[4];
    const float* W2        = (const float*)d_in[5];
    const float* b2        = (const float*)d_in[6];
    const float* Wc        = (const float*)d_in[7];
    const float* bc        = (const float*)d_in[8];
    float* out = (float*)d_out;

    char* ws = (char*)d_ws;
    size_t off = 0;
    auto alloc = [&](size_t elems) { void* p = ws + off; off += elems * 4; return p; };

    // --- zeroed region (one tiny memset, 16B-multiple) ---
    unsigned* bcur1 = (unsigned*)alloc(256);
    unsigned* bcur2 = (unsigned*)alloc(256);
    float*    pool  = (float*)   alloc(N_GRAPHS * HIDDEN);
    float*    cnt   = (float*)   alloc(N_GRAPHS);
    size_t zero_bytes = off;
    // --- non-zeroed ---
    float4*   info  = (float4*)  alloc((size_t)N_NODES * 4);        // 1.6 MB
    unsigned* tmp1  = (unsigned*)alloc((size_t)NBUCK * CAP);        // 12.8 MB
    ushort*   tmp2  = (ushort*)  alloc((size_t)NBUCK * CAP / 2);    // 6.4 MB
    int*      csr   = (int*)     alloc((size_t)NBUCK * CAP);        // 12.8 MB
    int*      rs    = (int*)     alloc(N_NODES);
    unsigned* indeg = (unsigned*)alloc(N_NODES);
    float*    nsA   = (float*)   alloc(N_NODES);
    float*    hs0   = (float*)   alloc(N_NODES);
    float*    U     = (float*)   alloc(129 * HIDDEN);
    float*    V     = (float*)   alloc(129 * HIDDEN);

    hipMemsetAsync(d_ws, 0, zero_bytes, stream);

    int pblocks = (N_EDGES + PCH - 1) / PCH;   // 391
    int nblocks = (N_NODES + 255) / 256;       // 391
    k_part      <<<pblocks, PTH, 0, stream>>>(src, dst, bcur1, bcur2, tmp1, tmp2, N_EDGES);
    k_ind_csr   <<<NBUCK, 1024, 0, stream>>>(bcur1, tmp1, bcur2, tmp2, indeg, nsA, hs0, rs, csr);
    k_conv1_info<<<nblocks, 256, 0, stream>>>(rs, csr, hs0, indeg, nsA, W1, b1, W2, U, V, info, N_NODES);
    k_conv2_pool<<<nblocks, 256, 0, stream>>>(rs, csr, info, indeg, U, V, graph_ids, b2, pool, cnt, N_NODES);
    k_final     <<<(N_GRAPHS * N_CLASSES + 255) / 256, 256, 0, stream>>>(pool, cnt, Wc, bc, out);
}